// Round 11
// baseline (566.612 us; speedup 1.0000x reference)
//
#include <hip/hip_runtime.h>
#include <math.h>

// Problem constants
static constexpr int Bn = 4, Pp = 512, C2 = 256, HEAD = 4, DHd = 64;
static constexpr int Ll = 1024, DIi = 512, Nn = 64, Rr = 16, KCc = 4;
static constexpr int XDW = 192;   // padded xdbl row stride

#define DEVI __device__ __forceinline__

DEVI float sigf(float x){ return 1.0f/(1.0f+__expf(-x)); }
DEVI float softplusf(float x){ return x > 20.f ? x : log1pf(__expf(x)); }

// bf16 split helpers (RNE hi, exact residual -> RNE lo)
DEVI unsigned short bfh(float f){
  unsigned int u = __float_as_uint(f);
  return (unsigned short)((u + 0x7FFFu + ((u>>16)&1u)) >> 16);
}
DEVI float bff(unsigned short h){ return __uint_as_float(((unsigned int)h)<<16); }
DEVI void wsplit(float v, unsigned short* __restrict__ h, unsigned short* __restrict__ l,
                 size_t i){
  unsigned short hh = bfh(v);
  h[i] = hh; l[i] = bfh(v - bff(hh));
}

typedef __attribute__((ext_vector_type(8))) short  bf8v;   // 8 bf16 in 4 VGPRs
typedef __attribute__((ext_vector_type(4))) float  f4v;
typedef __attribute__((ext_vector_type(8))) unsigned short u16x8;

// ---------------- generic fp32 -> hi/lo split ----------------
__global__ void k_split(const float* __restrict__ src, unsigned short* __restrict__ h,
                        unsigned short* __restrict__ l, int n){
  int i = blockIdx.x*256 + threadIdx.x;
  if (i < n) wsplit(src[i], h, l, i);
}

// ---------------- transpose x -> seq(+pos) fp32+split, x2 split ----------------
__global__ void k_transpose(const float* __restrict__ x, const float* __restrict__ rh,
                            const float* __restrict__ rw, float* __restrict__ seq,
                            unsigned short* __restrict__ sh, unsigned short* __restrict__ sl,
                            unsigned short* __restrict__ x2h, unsigned short* __restrict__ x2l){
  __shared__ float t[32][33];
  int b = blockIdx.z, c0 = blockIdx.y*32, l0 = blockIdx.x*32;
  for (int i = threadIdx.y; i < 32; i += 8)
    t[i][threadIdx.x] = x[((size_t)(b*Pp + c0 + i)*Ll) + l0 + threadIdx.x];
  __syncthreads();
  for (int i = threadIdx.y; i < 32; i += 8){
    int l = l0 + i, c = c0 + threadIdx.x;
    float v = t[threadIdx.x][i];
    if (c < C2){
      float pos = rh[c*32 + (l & 31)] + rw[c*32 + (l >> 5)];
      float vv = v + pos;
      size_t o = (size_t)(b*Ll + l)*C2 + c;
      seq[o] = vv;
      wsplit(vv, sh, sl, o);
    } else {
      size_t o = (size_t)(b*Ll + l)*C2 + (c - C2);
      wsplit(v, x2h, x2l, o);
    }
  }
}

// ---------------- split-operand MFMA GEMM, 64x64 tile ----------------
// C[m,n] = act( sum_k (Ah+Al)[m,k]*(Bh+Bl)[n,k] + bias[n] ).  Operands pre-split
// bf16 hi/lo ushort arrays (r10: in-loop fp32->bf16 split = ~320 VALU/thread/tile
// made GEMMs VALU-bound). Compute/barrier structure = r6-proven k_mgemmb.
__global__ void __launch_bounds__(256) k_hgemm(
    const unsigned short* __restrict__ Ahp, const unsigned short* __restrict__ Alp,
    const unsigned short* __restrict__ Bhp, const unsigned short* __restrict__ Blp,
    float* __restrict__ C, const float* __restrict__ bias,
    int M, int N, int K, int lda, int ldb, int ldc,
    long sA1, long sA2, long sB1, long sB2, long sC1, long sC2, int act)
{
  __shared__ __align__(16) unsigned short Ah[64*40], Al[64*40], Bh[64*40], Bl[64*40];
  int z = blockIdx.z;
  const unsigned short* Abh = Ahp + (size_t)((z>>2)*sA1 + (z&3)*sA2);
  const unsigned short* Abl = Alp + (size_t)((z>>2)*sA1 + (z&3)*sA2);
  const unsigned short* Bbh = Bhp + (size_t)((z>>2)*sB1 + (z&3)*sB2);
  const unsigned short* Bbl = Blp + (size_t)((z>>2)*sB1 + (z&3)*sB2);
  float* Cb = C + (size_t)((z>>2)*sC1 + (z&3)*sC2);
  int m0 = blockIdx.y*64, n0 = blockIdx.x*64;
  int t = threadIdx.x;
  int w = t >> 6, l = t & 63;
  int g = l >> 4, r = l & 15;
  int row0 = w*16;

  f4v acc[4];
  #pragma unroll
  for (int j=0;j<4;++j) acc[j] = (f4v){0.f,0.f,0.f,0.f};

  int sr = t >> 2;            // 0..63
  int sc = (t & 3) * 8;       // 0,8,16,24

  for (int k0 = 0; k0 < K; k0 += 32){
    size_t ao = (size_t)(m0+sr)*lda + k0 + sc;
    size_t bo = (size_t)(n0+sr)*ldb + k0 + sc;
    *(u16x8*)&Ah[sr*40+sc] = *(const u16x8*)&Abh[ao];
    *(u16x8*)&Al[sr*40+sc] = *(const u16x8*)&Abl[ao];
    *(u16x8*)&Bh[sr*40+sc] = *(const u16x8*)&Bbh[bo];
    *(u16x8*)&Bl[sr*40+sc] = *(const u16x8*)&Bbl[bo];
    __syncthreads();
    bf8v a_h = *(const bf8v*)&Ah[(row0+r)*40 + g*8];
    bf8v a_l = *(const bf8v*)&Al[(row0+r)*40 + g*8];
    #pragma unroll
    for (int j=0;j<4;++j){
      bf8v b_h = *(const bf8v*)&Bh[(j*16+r)*40 + g*8];
      bf8v b_l = *(const bf8v*)&Bl[(j*16+r)*40 + g*8];
      acc[j] = __builtin_amdgcn_mfma_f32_16x16x32_bf16(a_h, b_h, acc[j], 0, 0, 0);
      acc[j] = __builtin_amdgcn_mfma_f32_16x16x32_bf16(a_h, b_l, acc[j], 0, 0, 0);
      acc[j] = __builtin_amdgcn_mfma_f32_16x16x32_bf16(a_l, b_h, acc[j], 0, 0, 0);
    }
    __syncthreads();
  }
  #pragma unroll
  for (int j=0;j<4;++j){
    int n = n0 + j*16 + r;
    float bv = bias ? bias[n] : 0.f;
    #pragma unroll
    for (int q=0;q<4;++q){
      int m = m0 + row0 + g*4 + q;
      float v = acc[j][q] + bv;
      if (act == 1) v = sigf(v);
      Cb[(size_t)m*ldc + n] = v;
    }
  }
}

// ---------------- split-operand MFMA GEMM, 128x128 tile (energy & xz) ------------
__global__ void __launch_bounds__(256) k_h128(
    const unsigned short* __restrict__ Ahp, const unsigned short* __restrict__ Alp,
    const unsigned short* __restrict__ Bhp, const unsigned short* __restrict__ Blp,
    float* __restrict__ C, const float* __restrict__ bias,
    int M, int N, int K, int lda, int ldb, int ldc,
    long sA1, long sA2, long sB1, long sB2, long sC1, long sC2, int act)
{
  __shared__ __align__(16) unsigned short Ah[128*40], Al[128*40], Bh[128*40], Bl[128*40];
  int z = blockIdx.z;
  const unsigned short* Abh = Ahp + (size_t)((z>>2)*sA1 + (z&3)*sA2);
  const unsigned short* Abl = Alp + (size_t)((z>>2)*sA1 + (z&3)*sA2);
  const unsigned short* Bbh = Bhp + (size_t)((z>>2)*sB1 + (z&3)*sB2);
  const unsigned short* Bbl = Blp + (size_t)((z>>2)*sB1 + (z&3)*sB2);
  float* Cb = C + (size_t)((z>>2)*sC1 + (z&3)*sC2);
  int m0 = blockIdx.y*128, n0 = blockIdx.x*128;
  int t = threadIdx.x;
  int w = t >> 6, l = t & 63;
  int g = l >> 4, r = l & 15;
  int row0 = w*32;

  f4v acc[2][8];
  #pragma unroll
  for (int i=0;i<2;++i)
    #pragma unroll
    for (int j=0;j<8;++j) acc[i][j] = (f4v){0.f,0.f,0.f,0.f};

  int sr = t >> 1;            // 0..127
  int sc = (t & 1) * 16;      // 0,16

  for (int k0 = 0; k0 < K; k0 += 32){
    size_t ao = (size_t)(m0+sr)*lda + k0 + sc;
    size_t bo = (size_t)(n0+sr)*ldb + k0 + sc;
    *(u16x8*)&Ah[sr*40+sc]   = *(const u16x8*)&Abh[ao];
    *(u16x8*)&Ah[sr*40+sc+8] = *(const u16x8*)&Abh[ao+8];
    *(u16x8*)&Al[sr*40+sc]   = *(const u16x8*)&Abl[ao];
    *(u16x8*)&Al[sr*40+sc+8] = *(const u16x8*)&Abl[ao+8];
    *(u16x8*)&Bh[sr*40+sc]   = *(const u16x8*)&Bbh[bo];
    *(u16x8*)&Bh[sr*40+sc+8] = *(const u16x8*)&Bbh[bo+8];
    *(u16x8*)&Bl[sr*40+sc]   = *(const u16x8*)&Bbl[bo];
    *(u16x8*)&Bl[sr*40+sc+8] = *(const u16x8*)&Bbl[bo+8];
    __syncthreads();
    bf8v a_h0 = *(const bf8v*)&Ah[(row0+r)*40 + g*8];
    bf8v a_l0 = *(const bf8v*)&Al[(row0+r)*40 + g*8];
    bf8v a_h1 = *(const bf8v*)&Ah[(row0+16+r)*40 + g*8];
    bf8v a_l1 = *(const bf8v*)&Al[(row0+16+r)*40 + g*8];
    #pragma unroll
    for (int j=0;j<8;++j){
      bf8v b_h = *(const bf8v*)&Bh[(j*16+r)*40 + g*8];
      bf8v b_l = *(const bf8v*)&Bl[(j*16+r)*40 + g*8];
      acc[0][j] = __builtin_amdgcn_mfma_f32_16x16x32_bf16(a_h0, b_h, acc[0][j], 0, 0, 0);
      acc[0][j] = __builtin_amdgcn_mfma_f32_16x16x32_bf16(a_h0, b_l, acc[0][j], 0, 0, 0);
      acc[0][j] = __builtin_amdgcn_mfma_f32_16x16x32_bf16(a_l0, b_h, acc[0][j], 0, 0, 0);
      acc[1][j] = __builtin_amdgcn_mfma_f32_16x16x32_bf16(a_h1, b_h, acc[1][j], 0, 0, 0);
      acc[1][j] = __builtin_amdgcn_mfma_f32_16x16x32_bf16(a_h1, b_l, acc[1][j], 0, 0, 0);
      acc[1][j] = __builtin_amdgcn_mfma_f32_16x16x32_bf16(a_l1, b_h, acc[1][j], 0, 0, 0);
    }
    __syncthreads();
  }
  #pragma unroll
  for (int i=0;i<2;++i){
    #pragma unroll
    for (int j=0;j<8;++j){
      int n = n0 + j*16 + r;
      float bv = bias ? bias[n] : 0.f;
      #pragma unroll
      for (int q=0;q<4;++q){
        int m = m0 + row0 + i*16 + g*4 + q;
        float v = acc[i][j][q] + bv;
        if (act == 1) v = sigf(v);
        Cb[(size_t)m*ldc + n] = v;
      }
    }
  }
}

// ---------------- pad W_x -> split W_xp (192x512) ----------------
__global__ void k_padwx(const float* __restrict__ W_x, unsigned short* __restrict__ h,
                        unsigned short* __restrict__ l){
  int idx = blockIdx.x*256 + threadIdx.x;          // 192*512
  int row = idx >> 9;
  float v = (row < 144) ? W_x[(size_t)row*512 + (idx & 511)] : 0.f;
  wsplit(v, h, l, idx);
}

// ---------------- im2col (split out) ----------------
__global__ void k_im2col(const float* __restrict__ seq, unsigned short* __restrict__ h,
                         unsigned short* __restrict__ l){
  int idx = blockIdx.x*256 + threadIdx.x;          // B*L*768
  int j  = idx % 768;
  int bl = idx / 768;
  int kk = j >> 8, c = j & 255;
  int ll = bl & 1023, b = bl >> 10;
  int ls = ll + kk - 1;
  float v = 0.f;
  if (ls >= 0 && ls < Ll) v = seq[(size_t)(b*Ll + ls)*C2 + c];
  wsplit(v, h, l, idx);
}

// gate_w (O,I,3) -> split W2 (O, kk*256+i)
__global__ void k_packw(const float* __restrict__ gw, unsigned short* __restrict__ h,
                        unsigned short* __restrict__ l){
  int idx = blockIdx.x*256 + threadIdx.x;          // 256*768
  int j = idx % 768, o = idx / 768;
  int kk = j >> 8, i = j & 255;
  wsplit(gw[(size_t)(o*256 + i)*3 + kk], h, l, idx);
}

// ---------------- depthwise causal conv + SiLU (fp32 + split out) ----------------
__global__ void k_dwconv(const float* __restrict__ xz, const float* __restrict__ cw,
                         const float* __restrict__ cb, float* __restrict__ xs,
                         unsigned short* __restrict__ h, unsigned short* __restrict__ l){
  int idx = blockIdx.x*256 + threadIdx.x;          // B*L*512
  int d = idx & 511; int bl = idx >> 9; int ll = bl & 1023; int b = bl >> 10;
  float s = cb[d];
  #pragma unroll
  for (int kk = 0; kk < 4; ++kk){
    int ls = ll - 3 + kk;
    if (ls >= 0) s = fmaf(cw[d*4+kk], xz[(size_t)(b*Ll+ls)*1024 + d], s);
  }
  float v = s * sigf(s);
  xs[idx] = v;
  wsplit(v, h, l, idx);
}

// ---------------- pre-scan: dtT/dtuT (time-major) ----------------
__global__ void k_pret(const float* __restrict__ xdbl, const float* __restrict__ xs,
                       const float* __restrict__ W_dt, const float* __restrict__ b_dt,
                       float* __restrict__ dtT, float* __restrict__ dtuT){
  __shared__ float X[32][17];
  __shared__ float Wd[32][17];
  __shared__ float xsb[32][33];
  int b = blockIdx.z, d0 = blockIdx.y*32, l0 = blockIdx.x*32;
  int tx = threadIdx.x, ty = threadIdx.y;           // 32 x 8
  for (int i = ty; i < 32; i += 8){
    if (tx < 16)      X[i][tx]      = xdbl[(size_t)(b*Ll + l0 + i)*XDW + tx];
    else              Wd[i][tx-16]  = W_dt[(size_t)(d0 + i)*16 + tx - 16];
    xsb[i][tx] = xs[(size_t)(b*Ll + l0 + i)*512 + d0 + tx];
  }
  __syncthreads();
  for (int dy = ty; dy < 32; dy += 8){
    int d = d0 + dy;
    float v = b_dt[d];
    #pragma unroll
    for (int r = 0; r < 16; ++r) v = fmaf(Wd[dy][r], X[tx][r], v);
    float dt = softplusf(v);
    size_t o = ((size_t)(b*512 + d))*Ll + l0 + tx;
    dtT[o]  = dt;
    dtuT[o] = dt * xsb[tx][dy];
  }
}

// ---------------- selective scan v6 (unchanged from r10) ----------------
__global__ void __launch_bounds__(256, 1) k_scan6(
    const float* __restrict__ dtT, const float* __restrict__ dtuT,
    const float* __restrict__ xdbl, const float* __restrict__ A_log,
    float* __restrict__ yT){
  __shared__ float Bs[32*64];
  __shared__ float Cs[32*64];
  __shared__ float pb[4*32*65];
  int t = threadIdx.x;
  int w = t >> 6, lane = t & 63;
  int blk = blockIdx.x;                   // 0..511
  int b = blk >> 7, grp = blk & 127;
  int d = grp*4 + w;
  float Ac = -__expf(A_log[d*64 + lane]);
  float h = 0.f;
  size_t base = (size_t)b*Ll;
  size_t bd   = ((size_t)(b*512 + d))*Ll;
  int jl = lane & 31;
  bool lo = lane < 32;
  float* pbw = &pb[w*2080];
  for (int c0 = 0; c0 < Ll; c0 += 32){
    float dtv = 0.f, duv = 0.f;
    if (lo){
      dtv = dtT[bd + c0 + lane];
      duv = dtuT[bd + c0 + lane];
    }
    #pragma unroll
    for (int kk = 0; kk < 8; ++kk){
      int i = t + kk*256;
      int row = i >> 6, col = i & 63;
      size_t r2 = (base + c0 + row)*XDW;
      Bs[i] = xdbl[r2 + 16 + col];
      Cs[i] = xdbl[r2 + 80 + col];
    }
    __syncthreads();
    float ev[32], gv[32];
    #pragma unroll
    for (int l = 0; l < 32; ++l){
      float sdt = __shfl(dtv, l);
      float sdu = __shfl(duv, l);
      ev[l] = __expf(sdt*Ac);
      gv[l] = sdu*Bs[l*64 + lane];
    }
    #pragma unroll
    for (int l = 0; l < 32; ++l){
      h = fmaf(ev[l], h, gv[l]);
      pbw[l*65 + lane] = h*Cs[l*64 + lane];
    }
    __syncthreads();
    {
      const float* rp = &pbw[jl*65 + (lo ? 0 : 32)];
      float s0=0.f, s1=0.f, s2=0.f, s3=0.f;
      #pragma unroll
      for (int n = 0; n < 32; n += 4){
        s0 += rp[n]; s1 += rp[n+1]; s2 += rp[n+2]; s3 += rp[n+3];
      }
      float p = (s0+s1)+(s2+s3);
      p += __shfl_xor(p, 32);
      if (lo) yT[bd + c0 + jl] = p;
    }
    __syncthreads();
  }
}

// ---------------- yT -> y + epilogue, split out (feeds ym GEMM only) ------------
__global__ void k_ytrans(const float* __restrict__ yT, const float* __restrict__ xs,
                         const float* __restrict__ xz, const float* __restrict__ D_p,
                         unsigned short* __restrict__ h, unsigned short* __restrict__ l){
  __shared__ float t[32][33];
  int b = blockIdx.z, d0 = blockIdx.y*32, l0 = blockIdx.x*32;
  int tx = threadIdx.x, ty = threadIdx.y;
  for (int i = ty; i < 32; i += 8)
    t[i][tx] = yT[((size_t)(b*512 + d0 + i))*Ll + l0 + tx];
  __syncthreads();
  for (int i = ty; i < 32; i += 8){
    int d = d0 + tx;
    size_t bl = (size_t)b*Ll + l0 + i;
    float p  = t[tx][i];
    float u  = xs[bl*512 + d];
    float zv = xz[bl*1024 + 512 + d];
    float v = (p + D_p[d]*u) * (zv * sigf(zv));
    wsplit(v, h, l, bl*512 + d);
  }
}

// ---------------- pack attention A/B operands (split out) ----------------
__global__ void k_pack_ab(const float* __restrict__ qt, const float* __restrict__ kt,
                          const float* __restrict__ rhm, const float* __restrict__ rwm,
                          unsigned short* __restrict__ Ahp, unsigned short* __restrict__ Alp,
                          unsigned short* __restrict__ Bhp, unsigned short* __restrict__ Blp){
  int idx = blockIdx.x*256 + threadIdx.x;          // B*H*L*128
  int dd = idx & 127;
  int i  = (idx >> 7) & 1023;
  int h  = (idx >> 17) & 3;
  int b  = idx >> 19;
  float av, bv;
  if (dd < 64){
    size_t q = (size_t)(b*Ll + i)*C2 + h*64 + dd;
    av = qt[q]; bv = kt[q];
  } else {
    int d = dd - 64;
    av = rhm[(h*64+d)*32 + (i & 31)] + rwm[(h*64+d)*32 + (i >> 5)];
    bv = qt[(size_t)(b*Ll + i)*C2 + h*64 + d];
  }
  wsplit(av, Ahp, Alp, idx);
  wsplit(bv, Bhp, Blp, idx);
}

// ---------------- V transpose (split out): vt -> vT (B,256,L) ----------------
__global__ void k_vtrans(const float* __restrict__ vt, unsigned short* __restrict__ h,
                         unsigned short* __restrict__ l){
  __shared__ float t[32][33];
  int b = blockIdx.z, c0 = blockIdx.y*32, j0 = blockIdx.x*32;
  for (int i = threadIdx.y; i < 32; i += 8)
    t[i][threadIdx.x] = vt[(size_t)(b*Ll + j0 + i)*C2 + c0 + threadIdx.x];
  __syncthreads();
  for (int i = threadIdx.y; i < 32; i += 8){
    size_t o = ((size_t)(b*C2 + c0 + i))*Ll + j0 + threadIdx.x;
    wsplit(t[threadIdx.x][i], h, l, o);
  }
}

// ---------------- row softmax, IN-PLACE split output ----------------------------
// Row's 4KB becomes hi[1024] (ushort) then lo[1024]. All global reads precede
// barrier #1; split-writes happen after barrier #2 -> no intra-row race.
__global__ void __launch_bounds__(256) k_softmax(float* __restrict__ e){
  __shared__ float red[4];
  __shared__ float red2[4];
  size_t row = blockIdx.x;
  float* p = e + row*1024;
  int t = threadIdx.x;
  float v0 = p[t], v1 = p[t+256], v2 = p[t+512], v3 = p[t+768];
  float mx = fmaxf(fmaxf(v0,v1), fmaxf(v2,v3));
  #pragma unroll
  for (int off=32; off; off>>=1) mx = fmaxf(mx, __shfl_xor(mx, off));
  if ((t&63)==0) red[t>>6] = mx;
  __syncthreads();
  mx = fmaxf(fmaxf(red[0],red[1]), fmaxf(red[2],red[3]));
  v0 = __expf(v0-mx); v1 = __expf(v1-mx); v2 = __expf(v2-mx); v3 = __expf(v3-mx);
  float s = v0+v1+v2+v3;
  #pragma unroll
  for (int off=32; off; off>>=1) s += __shfl_xor(s, off);
  if ((t&63)==0) red2[t>>6] = s;
  __syncthreads();
  s = red2[0]+red2[1]+red2[2]+red2[3];
  float inv = 1.0f/s;
  unsigned short* ph = (unsigned short*)p;   // hi at [j], lo at [1024+j]
  float r0 = v0*inv, r1 = v1*inv, r2 = v2*inv, r3 = v3*inv;
  unsigned short h0 = bfh(r0), h1 = bfh(r1), h2 = bfh(r2), h3 = bfh(r3);
  ph[t]      = h0; ph[1024+t]      = bfh(r0 - bff(h0));
  ph[t+256]  = h1; ph[1024+t+256]  = bfh(r1 - bff(h1));
  ph[t+512]  = h2; ph[1024+t+512]  = bfh(r2 - bff(h2));
  ph[t+768]  = h3; ph[1024+t+768]  = bfh(r3 - bff(h3));
}

// ---------------- fused ym*ctx + reshape-reinterpret (split out) ----------------
__global__ void k_mulshuf(const float* __restrict__ ym, const float* __restrict__ ctx,
                          unsigned short* __restrict__ h, unsigned short* __restrict__ l){
  __shared__ float t[32][33];
  int b = blockIdx.z >> 2, s1 = blockIdx.z & 3;
  int c0 = blockIdx.y*32, s00 = blockIdx.x*32;
  for (int i = threadIdx.y; i < 32; i += 8){
    int c = c0 + i;
    int ll = c*4 + s1;
    size_t off = ((size_t)(b*Ll + ll))*C2 + s00 + threadIdx.x;
    t[i][threadIdx.x] = ym[off] * ctx[off];
  }
  __syncthreads();
  for (int i = threadIdx.y; i < 32; i += 8){
    int s0 = s00 + i, c = c0 + threadIdx.x;
    int s = s1*256 + s0;
    wsplit(t[threadIdx.x][i], h, l, ((size_t)(b*Ll + s))*C2 + c);
  }
}

// ---------------- scalar gates ga/gb ----------------
__global__ void __launch_bounds__(256) k_gates(
    const float* __restrict__ ap, const float* __restrict__ bp,
    const float* __restrict__ Wg, const float* __restrict__ bg, float* __restrict__ g){
  __shared__ float ra[4], rb[4];
  int bl = blockIdx.x; int t = threadIdx.x;
  float sa = 0.f, sb = 0.f;
  const float* a = ap + (size_t)bl*512;
  const float* bq = bp + (size_t)bl*512;
  for (int pp = t; pp < 512; pp += 256){ float w = Wg[pp]; sa = fmaf(w, a[pp], sa); sb = fmaf(w, bq[pp], sb); }
  #pragma unroll
  for (int off=32; off; off>>=1){ sa += __shfl_xor(sa,off); sb += __shfl_xor(sb,off); }
  if ((t&63)==0){ ra[t>>6]=sa; rb[t>>6]=sb; }
  __syncthreads();
  if (t==0){
    float b0 = bg[0];
    g[bl]        = sigf(ra[0]+ra[1]+ra[2]+ra[3] + b0);
    g[4096 + bl] = sigf(rb[0]+rb[1]+rb[2]+rb[3] + b0);
  }
}

// ---------------- final gated combine, transposed write ----------------
__global__ void k_final(const float* __restrict__ ap, const float* __restrict__ bp,
                        const float* __restrict__ g, float* __restrict__ out){
  int bpid = blockIdx.x; int b = bpid >> 9, p = bpid & 511;
  for (int l = threadIdx.x; l < Ll; l += 256){
    int bl = b*Ll + l;
    float ga = g[bl], gb = g[4096 + bl];
    out[((size_t)(b*Pp + p) << 10) + l] =
        ga*ap[(size_t)bl*512 + p] + gb*bp[(size_t)bl*512 + p];
  }
}

// ---------------- host helpers ----------------
typedef unsigned short us;
static inline void hgemm(hipStream_t s, const us* Ah, const us* Al, const us* Bh, const us* Bl,
                         float* C, const float* bias, int M, int N, int K,
                         int lda, int ldb, int ldc, int act){
  dim3 g(N/64, M/64, 1), blk(256);
  k_hgemm<<<g, blk, 0, s>>>(Ah,Al,Bh,Bl,C,bias,M,N,K,lda,ldb,ldc, 0,0,0,0,0,0, act);
}

extern "C" void kernel_launch(void* const* d_in, const int* in_sizes, int n_in,
                              void* d_out, int out_size, void* d_ws, size_t ws_size,
                              hipStream_t stream) {
  const float* x      = (const float*)d_in[0];
  const float* rh_c   = (const float*)d_in[1];
  const float* rw_c   = (const float*)d_in[2];
  const float* gate_w = (const float*)d_in[3];
  const float* gate_b = (const float*)d_in[4];
  const float* W_in   = (const float*)d_in[5];
  const float* conv_w = (const float*)d_in[6];
  const float* conv_b = (const float*)d_in[7];
  const float* W_x    = (const float*)d_in[8];
  const float* W_dt   = (const float*)d_in[9];
  const float* b_dt   = (const float*)d_in[10];
  const float* A_log  = (const float*)d_in[11];
  const float* D_p    = (const float*)d_in[12];
  const float* W_out  = (const float*)d_in[13];
  const float* Wq     = (const float*)d_in[14];
  const float* bq     = (const float*)d_in[15];
  const float* Wk     = (const float*)d_in[16];
  const float* bk     = (const float*)d_in[17];
  const float* Wv     = (const float*)d_in[18];
  const float* bv     = (const float*)d_in[19];
  const float* rhm    = (const float*)d_in[20];
  const float* rwm    = (const float*)d_in[21];
  // d_in[22] reg_qk, d_in[23] reg_v: provably dead
  const float* Wa     = (const float*)d_in[24];
  const float* ba     = (const float*)d_in[25];
  const float* Wb     = (const float*)d_in[26];
  const float* bb     = (const float*)d_in[27];
  const float* Wg     = (const float*)d_in[28];
  const float* bg     = (const float*)d_in[29];
  float* out = (float*)d_out;
  float* ws  = (float*)d_ws;

  // fp32 slot layout (floats), ~131 MB total — unchanged footprint
  float* seq    = ws;                       // 1,048,576
  float* x2seq  = ws +  1048576;            // 1,048,576 (x2 split lives here)
  float* qt     = ws +  2097152;            // 1,048,576 (later: xs-hi, then out2 split)
  float* kt     = ws +  3145728;            // 1,048,576 (mamba: weight splits)
  float* vt     = ws +  4194304;            // 1,048,576 (later: xs-lo)
  float* Abuf   = ws +  5242880;            // 2,097,152 (energy A split)
  float* Bbuf   = ws +  7340032;            // 2,097,152 (energy B split)
  float* arena  = ws +  9437184;            // 16,777,216
  float* out2   = ws + 26214400;            // 1,048,576
  float* out1   = ws + 27262976;            // 1,048,576 (seq split, then out1 split)
  float* aproj  = ws + 28311552;            // 2,097,152 (vT split parks here)
  float* bproj  = ws + 30408704;            // 2,097,152
  float* gates  = ws + 32505856;            // 8,192
  float* W2     = ws + 32514048;            // 196,608 (W2 split)
  // arena sub-layout (mamba phase):
  float* A2   = arena;                      // 3,145,728 (A2 split)
  float* ctx  = arena +  3145728;           // 1,048,576
  float* xz   = arena +  4194304;           // 4,194,304
  float* xs   = arena +  8388608;           // 2,097,152
  float* xdbl = arena + 10485760;           // 786,432 (stride 192)
  float* yT   = arena + 11272192;           // 2,097,152
  float* yb   = arena + 13369344;           // 2,097,152 (yb split)
  float* ym   = arena + 15466496;           // 1,048,576
  float* energy = arena;                    // attention phase

  // ushort split views
  us* seqh = (us*)out1;      us* seql = seqh + 1048576;
  us* x2h  = (us*)x2seq;     us* x2l  = x2h + 1048576;
  us* eAh  = (us*)Abuf;      us* eAl  = eAh + 2097152;
  us* eBh  = (us*)Bbuf;      us* eBl  = eBh + 2097152;
  us* vTh  = (us*)aproj;     us* vTl  = vTh + 1048576;
  us* Wqh  = (us*)arena;     us* Wql  = Wqh + 65536;
  us* Wkh  = Wqh + 131072;   us* Wkl  = Wqh + 196608;
  us* Wvh  = Wqh + 262144;   us* Wvl  = Wqh + 327680;
  us* Ph   = (us*)energy;    us* Pl   = Ph + 1024;   // per-row interleave, lda=2048
  us* A2h  = (us*)A2;        us* A2l  = A2h + 3145728;
  us* W2h  = (us*)W2;        us* W2l  = W2h + 196608;
  us* Wm   = (us*)kt;        // mamba weight splits (kt free after pack_ab)
  us* Winh = Wm;             us* Winl = Wm + 262144;
  us* Woh  = Wm + 524288;    us* Wol  = Wm + 655360;
  us* Wah  = Wm + 786432;    us* Wal  = Wm + 917504;
  us* Wbh  = Wm + 1048576;   us* Wbl  = Wm + 1179648;
  us* Wxh  = Wm + 1310720;   us* Wxl  = Wm + 1409024;
  us* xsh  = (us*)qt;        us* xsl  = (us*)vt;
  us* ybh  = (us*)yb;        us* ybl  = ybh + 2097152;
  us* o1h  = (us*)out1;      us* o1l  = o1h + 1048576;  // overwrites dead seq split
  us* o2h  = (us*)qt;        us* o2l  = o2h + 1048576;  // overwrites dead xs-hi
  float* dtT  = Abuf;        float* dtuT = Bbuf;        // mamba phase reuse

  // 1. transpose: seq fp32 + seq split + x2 split
  k_transpose<<<dim3(32,16,4), dim3(32,8), 0, stream>>>(x, rh_c, rw_c, seq,
                                                        seqh, seql, x2h, x2l);

  // ---- attention ----
  k_split<<<256, 256, 0, stream>>>(Wq, Wqh, Wql, 65536);
  k_split<<<256, 256, 0, stream>>>(Wk, Wkh, Wkl, 65536);
  k_split<<<256, 256, 0, stream>>>(Wv, Wvh, Wvl, 65536);
  hgemm(stream, x2h, x2l, Wqh, Wql, qt, bq, 4096,256,256, 256,256,256, 0);
  hgemm(stream, x2h, x2l, Wkh, Wkl, kt, bk, 4096,256,256, 256,256,256, 0);
  hgemm(stream, x2h, x2l, Wvh, Wvl, vt, bv, 4096,256,256, 256,256,256, 0);
  k_pack_ab<<<8192, 256, 0, stream>>>(qt, kt, rhm, rwm, eAh, eAl, eBh, eBl);
  k_vtrans<<<dim3(32,8,4), dim3(32,8), 0, stream>>>(vt, vTh, vTl);
  // energy[z] (M=N=1024,K=128), z=b*4+h, 128² tile
  {
    dim3 g(8, 8, 16), blk(256);
    k_h128<<<g, blk, 0, stream>>>(eAh, eAl, eBh, eBl, energy, nullptr,
        1024,1024,128, 128,128,1024,
        4L*131072, 131072, 4L*131072, 131072, 4L*1048576, 1048576, 0);
  }
  k_softmax<<<16384, 256, 0, stream>>>(energy);   // in-place split
  // PV: out2[b,i,h*64+d] = sum_j P[z][i,j] * vT[b,h*64+d,j]
  {
    dim3 g(1, 16, 16), blk(256);
    k_hgemm<<<g, blk, 0, stream>>>(Ph, Pl, vTh, vTl, out2, nullptr,
        1024,64,1024, 2048,1024,256,
        8388608, 2097152, 262144, 65536, 262144, 64, 0);
  }

  // ---- mamba (arena reused; kt/qt/vt free for splits) ----
  k_packw<<<768, 256, 0, stream>>>(gate_w, W2h, W2l);
  k_padwx<<<384, 256, 0, stream>>>(W_x, Wxh, Wxl);
  k_split<<<1024, 256, 0, stream>>>(W_in, Winh, Winl, 262144);
  k_split<<<512, 256, 0, stream>>>(W_out, Woh, Wol, 131072);
  k_split<<<512, 256, 0, stream>>>(Wa, Wah, Wal, 131072);
  k_split<<<512, 256, 0, stream>>>(Wb, Wbh, Wbl, 131072);
  k_im2col<<<12288, 256, 0, stream>>>(seq, A2h, A2l);
  hgemm(stream, A2h, A2l, W2h, W2l, ctx, gate_b, 4096,256,768, 768,768,256, 1);
  // xz = seq @ W_in^T, 128² tile
  {
    dim3 g(8, 32, 1), blk(256);
    k_h128<<<g, blk, 0, stream>>>(seqh, seql, Winh, Winl, xz, nullptr,
        4096,1024,256, 256,256,1024, 0,0,0,0,0,0, 0);
  }
  k_dwconv<<<8192, 256, 0, stream>>>(xz, conv_w, conv_b, xs, xsh, xsl);
  hgemm(stream, xsh, xsl, Wxh, Wxl, xdbl, nullptr, 4096,192,512, 512,512,XDW, 0);
  k_pret<<<dim3(32,16,4), dim3(32,8), 0, stream>>>(xdbl, xs, W_dt, b_dt, dtT, dtuT);
  k_scan6<<<512, 256, 0, stream>>>(dtT, dtuT, xdbl, A_log, yT);
  k_ytrans<<<dim3(32,16,4), dim3(32,8), 0, stream>>>(yT, xs, xz, D_p, ybh, ybl);
  hgemm(stream, ybh, ybl, Woh, Wol, ym, nullptr, 4096,256,512, 512,512,256, 0);
  k_mulshuf<<<dim3(8,8,16), dim3(32,8), 0, stream>>>(ym, ctx, o1h, o1l);

  // ---- fusion head ----
  hgemm(stream, o1h, o1l, Wah, Wal, aproj, ba, 4096,512,256, 256,256,512, 0);
  k_split<<<4096, 256, 0, stream>>>(out2, o2h, o2l, 1048576);
  hgemm(stream, o2h, o2l, Wbh, Wbl, bproj, bb, 4096,512,256, 256,256,512, 0);
  k_gates<<<4096, 256, 0, stream>>>(aproj, bproj, Wg, bg, gates);
  k_final<<<2048, 256, 0, stream>>>(aproj, bproj, gates, out);
}

// Round 12
// 534.292 us; speedup vs baseline: 1.0605x; 1.0605x over previous
//
#include <hip/hip_runtime.h>
#include <math.h>

// Problem constants
static constexpr int Bn = 4, Pp = 512, C2 = 256, HEAD = 4, DHd = 64;
static constexpr int Ll = 1024, DIi = 512, Nn = 64, Rr = 16, KCc = 4;
static constexpr int XDW = 192;   // padded xdbl row stride

#define DEVI __device__ __forceinline__

DEVI float sigf(float x){ return 1.0f/(1.0f+__expf(-x)); }
DEVI float softplusf(float x){ return x > 20.f ? x : log1pf(__expf(x)); }

// bf16 split helpers (RNE hi, exact residual -> RNE lo)
DEVI unsigned short bfh(float f){
  unsigned int u = __float_as_uint(f);
  return (unsigned short)((u + 0x7FFFu + ((u>>16)&1u)) >> 16);
}
DEVI float bff(unsigned short h){ return __uint_as_float(((unsigned int)h)<<16); }
DEVI void wsplit(float v, unsigned short* __restrict__ h, unsigned short* __restrict__ l,
                 size_t i){
  unsigned short hh = bfh(v);
  h[i] = hh; l[i] = bfh(v - bff(hh));
}

typedef __attribute__((ext_vector_type(8))) short  bf8v;
typedef __attribute__((ext_vector_type(4))) float  f4v;
typedef __attribute__((ext_vector_type(8))) unsigned short u16x8;
typedef unsigned short us;

// ---------------- transpose x -> seq(+pos) fp32+split, x2 split ----------------
__global__ void k_transpose(const float* __restrict__ x, const float* __restrict__ rh,
                            const float* __restrict__ rw, float* __restrict__ seq,
                            us* __restrict__ sh, us* __restrict__ sl,
                            us* __restrict__ x2h, us* __restrict__ x2l){
  __shared__ float t[32][33];
  int b = blockIdx.z, c0 = blockIdx.y*32, l0 = blockIdx.x*32;
  for (int i = threadIdx.y; i < 32; i += 8)
    t[i][threadIdx.x] = x[((size_t)(b*Pp + c0 + i)*Ll) + l0 + threadIdx.x];
  __syncthreads();
  for (int i = threadIdx.y; i < 32; i += 8){
    int l = l0 + i, c = c0 + threadIdx.x;
    float v = t[threadIdx.x][i];
    if (c < C2){
      float pos = rh[c*32 + (l & 31)] + rw[c*32 + (l >> 5)];
      float vv = v + pos;
      size_t o = (size_t)(b*Ll + l)*C2 + c;
      seq[o] = vv;
      wsplit(vv, sh, sl, o);
    } else {
      size_t o = (size_t)(b*Ll + l)*C2 + (c - C2);
      wsplit(v, x2h, x2l, o);
    }
  }
}

// ---------------- attention weight prep: Wqkv concat split + bias concat --------
__global__ void k_wprep_a(const float* __restrict__ Wq, const float* __restrict__ Wk,
                          const float* __restrict__ Wv, const float* __restrict__ bq,
                          const float* __restrict__ bk, const float* __restrict__ bv,
                          us* __restrict__ wh, us* __restrict__ wl,
                          float* __restrict__ bqkv){
  int i = blockIdx.x*256 + threadIdx.x;
  if (i < 196608){
    int w = i >> 16, j = i & 65535;
    float v = (w==0 ? Wq[j] : (w==1 ? Wk[j] : Wv[j]));
    wsplit(v, wh, wl, i);
  } else if (i < 197376){
    int j = i - 196608;
    bqkv[j] = (j < 256) ? bq[j] : (j < 512 ? bk[j-256] : bv[j-512]);
  }
}

// ---------------- mamba weight prep (one kernel; r11 destinations) --------------
__global__ void k_wprep_m(const float* __restrict__ W_in, const float* __restrict__ W_out,
                          const float* __restrict__ Wa, const float* __restrict__ Wb,
                          const float* __restrict__ gate_w, const float* __restrict__ W_x,
                          us* __restrict__ Winh, us* __restrict__ Winl,
                          us* __restrict__ Woh,  us* __restrict__ Wol,
                          us* __restrict__ Wah,  us* __restrict__ Wal,
                          us* __restrict__ Wbh,  us* __restrict__ Wbl,
                          us* __restrict__ W2h,  us* __restrict__ W2l,
                          us* __restrict__ Wxh,  us* __restrict__ Wxl){
  int i = blockIdx.x*256 + threadIdx.x;
  if (i < 262144){ wsplit(W_in[i], Winh, Winl, i); return; }
  i -= 262144;
  if (i < 131072){ wsplit(W_out[i], Woh, Wol, i); return; }
  i -= 131072;
  if (i < 131072){ wsplit(Wa[i], Wah, Wal, i); return; }
  i -= 131072;
  if (i < 131072){ wsplit(Wb[i], Wbh, Wbl, i); return; }
  i -= 131072;
  if (i < 196608){
    int o = i / 768, col = i % 768;
    int kk = col >> 8, c = col & 255;
    wsplit(gate_w[(size_t)(o*256 + c)*3 + kk], W2h, W2l, i); return;
  }
  i -= 196608;
  if (i < 98304){
    int row = i >> 9;
    float v = (row < 144) ? W_x[(size_t)row*512 + (i & 511)] : 0.f;
    wsplit(v, Wxh, Wxl, i);
  }
}

// ---------------- split-operand MFMA GEMM, 64x64 tile (r6-r11 proven core) ------
// If Ch!=null: write split output to Ch/Cl (same index) instead of fp32 C.
__global__ void __launch_bounds__(256) k_hgemm(
    const us* __restrict__ Ahp, const us* __restrict__ Alp,
    const us* __restrict__ Bhp, const us* __restrict__ Blp,
    float* __restrict__ C, const float* __restrict__ bias,
    int M, int N, int K, int lda, int ldb, int ldc,
    long sA1, long sA2, long sB1, long sB2, long sC1, long sC2, int act,
    us* __restrict__ Chp, us* __restrict__ Clp)
{
  __shared__ __align__(16) us Ah[64*40], Al[64*40], Bh[64*40], Bl[64*40];
  int z = blockIdx.z;
  const us* Abh = Ahp + (size_t)((z>>2)*sA1 + (z&3)*sA2);
  const us* Abl = Alp + (size_t)((z>>2)*sA1 + (z&3)*sA2);
  const us* Bbh = Bhp + (size_t)((z>>2)*sB1 + (z&3)*sB2);
  const us* Bbl = Blp + (size_t)((z>>2)*sB1 + (z&3)*sB2);
  size_t zco = (size_t)((z>>2)*sC1 + (z&3)*sC2);
  int m0 = blockIdx.y*64, n0 = blockIdx.x*64;
  int t = threadIdx.x;
  int w = t >> 6, l = t & 63;
  int g = l >> 4, r = l & 15;
  int row0 = w*16;

  f4v acc[4];
  #pragma unroll
  for (int j=0;j<4;++j) acc[j] = (f4v){0.f,0.f,0.f,0.f};

  int sr = t >> 2;
  int sc = (t & 3) * 8;

  for (int k0 = 0; k0 < K; k0 += 32){
    size_t ao = (size_t)(m0+sr)*lda + k0 + sc;
    size_t bo = (size_t)(n0+sr)*ldb + k0 + sc;
    *(u16x8*)&Ah[sr*40+sc] = *(const u16x8*)&Abh[ao];
    *(u16x8*)&Al[sr*40+sc] = *(const u16x8*)&Abl[ao];
    *(u16x8*)&Bh[sr*40+sc] = *(const u16x8*)&Bbh[bo];
    *(u16x8*)&Bl[sr*40+sc] = *(const u16x8*)&Bbl[bo];
    __syncthreads();
    bf8v a_h = *(const bf8v*)&Ah[(row0+r)*40 + g*8];
    bf8v a_l = *(const bf8v*)&Al[(row0+r)*40 + g*8];
    #pragma unroll
    for (int j=0;j<4;++j){
      bf8v b_h = *(const bf8v*)&Bh[(j*16+r)*40 + g*8];
      bf8v b_l = *(const bf8v*)&Bl[(j*16+r)*40 + g*8];
      acc[j] = __builtin_amdgcn_mfma_f32_16x16x32_bf16(a_h, b_h, acc[j], 0, 0, 0);
      acc[j] = __builtin_amdgcn_mfma_f32_16x16x32_bf16(a_h, b_l, acc[j], 0, 0, 0);
      acc[j] = __builtin_amdgcn_mfma_f32_16x16x32_bf16(a_l, b_h, acc[j], 0, 0, 0);
    }
    __syncthreads();
  }
  #pragma unroll
  for (int j=0;j<4;++j){
    int n = n0 + j*16 + r;
    float bv = bias ? bias[n] : 0.f;
    #pragma unroll
    for (int q=0;q<4;++q){
      int m = m0 + row0 + g*4 + q;
      float v = acc[j][q] + bv;
      if (act == 1) v = sigf(v);
      size_t idx = zco + (size_t)m*ldc + n;
      if (Chp) wsplit(v, Chp, Clp, idx);
      else     C[idx] = v;
    }
  }
}

// ---------------- split-operand MFMA GEMM, 128x128 tile (energy & xz) ------------
__global__ void __launch_bounds__(256) k_h128(
    const us* __restrict__ Ahp, const us* __restrict__ Alp,
    const us* __restrict__ Bhp, const us* __restrict__ Blp,
    float* __restrict__ C, const float* __restrict__ bias,
    int M, int N, int K, int lda, int ldb, int ldc,
    long sA1, long sA2, long sB1, long sB2, long sC1, long sC2, int act)
{
  __shared__ __align__(16) us Ah[128*40], Al[128*40], Bh[128*40], Bl[128*40];
  int z = blockIdx.z;
  const us* Abh = Ahp + (size_t)((z>>2)*sA1 + (z&3)*sA2);
  const us* Abl = Alp + (size_t)((z>>2)*sA1 + (z&3)*sA2);
  const us* Bbh = Bhp + (size_t)((z>>2)*sB1 + (z&3)*sB2);
  const us* Bbl = Blp + (size_t)((z>>2)*sB1 + (z&3)*sB2);
  float* Cb = C + (size_t)((z>>2)*sC1 + (z&3)*sC2);
  int m0 = blockIdx.y*128, n0 = blockIdx.x*128;
  int t = threadIdx.x;
  int w = t >> 6, l = t & 63;
  int g = l >> 4, r = l & 15;
  int row0 = w*32;

  f4v acc[2][8];
  #pragma unroll
  for (int i=0;i<2;++i)
    #pragma unroll
    for (int j=0;j<8;++j) acc[i][j] = (f4v){0.f,0.f,0.f,0.f};

  int sr = t >> 1;
  int sc = (t & 1) * 16;

  for (int k0 = 0; k0 < K; k0 += 32){
    size_t ao = (size_t)(m0+sr)*lda + k0 + sc;
    size_t bo = (size_t)(n0+sr)*ldb + k0 + sc;
    *(u16x8*)&Ah[sr*40+sc]   = *(const u16x8*)&Abh[ao];
    *(u16x8*)&Ah[sr*40+sc+8] = *(const u16x8*)&Abh[ao+8];
    *(u16x8*)&Al[sr*40+sc]   = *(const u16x8*)&Abl[ao];
    *(u16x8*)&Al[sr*40+sc+8] = *(const u16x8*)&Abl[ao+8];
    *(u16x8*)&Bh[sr*40+sc]   = *(const u16x8*)&Bbh[bo];
    *(u16x8*)&Bh[sr*40+sc+8] = *(const u16x8*)&Bbh[bo+8];
    *(u16x8*)&Bl[sr*40+sc]   = *(const u16x8*)&Bbl[bo];
    *(u16x8*)&Bl[sr*40+sc+8] = *(const u16x8*)&Bbl[bo+8];
    __syncthreads();
    bf8v a_h0 = *(const bf8v*)&Ah[(row0+r)*40 + g*8];
    bf8v a_l0 = *(const bf8v*)&Al[(row0+r)*40 + g*8];
    bf8v a_h1 = *(const bf8v*)&Ah[(row0+16+r)*40 + g*8];
    bf8v a_l1 = *(const bf8v*)&Al[(row0+16+r)*40 + g*8];
    #pragma unroll
    for (int j=0;j<8;++j){
      bf8v b_h = *(const bf8v*)&Bh[(j*16+r)*40 + g*8];
      bf8v b_l = *(const bf8v*)&Bl[(j*16+r)*40 + g*8];
      acc[0][j] = __builtin_amdgcn_mfma_f32_16x16x32_bf16(a_h0, b_h, acc[0][j], 0, 0, 0);
      acc[0][j] = __builtin_amdgcn_mfma_f32_16x16x32_bf16(a_h0, b_l, acc[0][j], 0, 0, 0);
      acc[0][j] = __builtin_amdgcn_mfma_f32_16x16x32_bf16(a_l0, b_h, acc[0][j], 0, 0, 0);
      acc[1][j] = __builtin_amdgcn_mfma_f32_16x16x32_bf16(a_h1, b_h, acc[1][j], 0, 0, 0);
      acc[1][j] = __builtin_amdgcn_mfma_f32_16x16x32_bf16(a_h1, b_l, acc[1][j], 0, 0, 0);
      acc[1][j] = __builtin_amdgcn_mfma_f32_16x16x32_bf16(a_l1, b_h, acc[1][j], 0, 0, 0);
    }
    __syncthreads();
  }
  #pragma unroll
  for (int i=0;i<2;++i){
    #pragma unroll
    for (int j=0;j<8;++j){
      int n = n0 + j*16 + r;
      float bv = bias ? bias[n] : 0.f;
      #pragma unroll
      for (int q=0;q<4;++q){
        int m = m0 + row0 + i*16 + g*4 + q;
        float v = acc[i][j][q] + bv;
        if (act == 1) v = sigf(v);
        Cb[(size_t)m*ldc + n] = v;
      }
    }
  }
}

// ---------------- im2col (split out) ----------------
__global__ void k_im2col(const float* __restrict__ seq, us* __restrict__ h,
                         us* __restrict__ l){
  int idx = blockIdx.x*256 + threadIdx.x;
  int j  = idx % 768;
  int bl = idx / 768;
  int kk = j >> 8, c = j & 255;
  int ll = bl & 1023, b = bl >> 10;
  int ls = ll + kk - 1;
  float v = 0.f;
  if (ls >= 0 && ls < Ll) v = seq[(size_t)(b*Ll + ls)*C2 + c];
  wsplit(v, h, l, idx);
}

// ---------------- depthwise causal conv + SiLU (fp32 + split out) ----------------
__global__ void k_dwconv(const float* __restrict__ xz, const float* __restrict__ cw,
                         const float* __restrict__ cb, float* __restrict__ xs,
                         us* __restrict__ h, us* __restrict__ l){
  int idx = blockIdx.x*256 + threadIdx.x;
  int d = idx & 511; int bl = idx >> 9; int ll = bl & 1023; int b = bl >> 10;
  float s = cb[d];
  #pragma unroll
  for (int kk = 0; kk < 4; ++kk){
    int ls = ll - 3 + kk;
    if (ls >= 0) s = fmaf(cw[d*4+kk], xz[(size_t)(b*Ll+ls)*1024 + d], s);
  }
  float v = s * sigf(s);
  xs[idx] = v;
  wsplit(v, h, l, idx);
}

// ---------------- pre-scan: dtT/dtuT (time-major) ----------------
__global__ void k_pret(const float* __restrict__ xdbl, const float* __restrict__ xs,
                       const float* __restrict__ W_dt, const float* __restrict__ b_dt,
                       float* __restrict__ dtT, float* __restrict__ dtuT){
  __shared__ float X[32][17];
  __shared__ float Wd[32][17];
  __shared__ float xsb[32][33];
  int b = blockIdx.z, d0 = blockIdx.y*32, l0 = blockIdx.x*32;
  int tx = threadIdx.x, ty = threadIdx.y;
  for (int i = ty; i < 32; i += 8){
    if (tx < 16)      X[i][tx]      = xdbl[(size_t)(b*Ll + l0 + i)*XDW + tx];
    else              Wd[i][tx-16]  = W_dt[(size_t)(d0 + i)*16 + tx - 16];
    xsb[i][tx] = xs[(size_t)(b*Ll + l0 + i)*512 + d0 + tx];
  }
  __syncthreads();
  for (int dy = ty; dy < 32; dy += 8){
    int d = d0 + dy;
    float v = b_dt[d];
    #pragma unroll
    for (int r = 0; r < 16; ++r) v = fmaf(Wd[dy][r], X[tx][r], v);
    float dt = softplusf(v);
    size_t o = ((size_t)(b*512 + d))*Ll + l0 + tx;
    dtT[o]  = dt;
    dtuT[o] = dt * xsb[tx][dy];
  }
}

// ---------------- selective scan v7: reg-prefetch double-buffer -----------------
// v5/v6 structure + next-chunk B/C/dt loads held in 16 statically-indexed regs,
// issued right after barrier 1 so vmcnt-wait lands after a chunk of compute
// (r9-r11: bulk-synchronous stage stall = ~8000cy/chunk at 2 blocks/CU).
__global__ void __launch_bounds__(256, 2) k_scan7(
    const float* __restrict__ dtT, const float* __restrict__ dtuT,
    const float* __restrict__ xdbl, const float* __restrict__ A_log,
    float* __restrict__ yT){
  __shared__ float Bs[32*64];
  __shared__ float Cs[32*64];
  __shared__ float pb[4*32*65];
  int t = threadIdx.x;
  int w = t >> 6, lane = t & 63;
  int blk = blockIdx.x;                   // 0..511
  int b = blk >> 7, grp = blk & 127;
  int d = grp*4 + w;
  float Ac = -__expf(A_log[d*64 + lane]);
  float h = 0.f;
  size_t base = (size_t)b*Ll;
  size_t bd   = ((size_t)(b*512 + d))*Ll;
  int jl = lane & 31;
  bool lo = lane < 32;
  float* pbw = &pb[w*2080];
  // prefetch chunk 0
  float rB[8], rC[8];
  float dtv = 0.f, duv = 0.f;
  #pragma unroll
  for (int kk = 0; kk < 8; ++kk){
    int i = t + kk*256;
    int row = i >> 6, col = i & 63;
    size_t r2 = (base + row)*XDW;
    rB[kk] = xdbl[r2 + 16 + col];
    rC[kk] = xdbl[r2 + 80 + col];
  }
  if (lo){ dtv = dtT[bd + lane]; duv = dtuT[bd + lane]; }
  for (int c0 = 0; c0 < Ll; c0 += 32){
    // commit prefetched regs to LDS (vmcnt wait covered by previous chunk compute)
    #pragma unroll
    for (int kk = 0; kk < 8; ++kk){
      int i = t + kk*256;
      Bs[i] = rB[kk]; Cs[i] = rC[kk];
    }
    float dtc = dtv, duc = duv;
    __syncthreads();
    // issue next-chunk loads (overlap with compute below)
    int c1 = c0 + 32;
    if (c1 < Ll){
      #pragma unroll
      for (int kk = 0; kk < 8; ++kk){
        int i = t + kk*256;
        int row = i >> 6, col = i & 63;
        size_t r2 = (base + c1 + row)*XDW;
        rB[kk] = xdbl[r2 + 16 + col];
        rC[kk] = xdbl[r2 + 80 + col];
      }
      if (lo){ dtv = dtT[bd + c1 + lane]; duv = dtuT[bd + c1 + lane]; }
    }
    // compute phase
    float ev[32], gv[32];
    #pragma unroll
    for (int l = 0; l < 32; ++l){
      float sdt = __shfl(dtc, l);
      float sdu = __shfl(duc, l);
      ev[l] = __expf(sdt*Ac);
      gv[l] = sdu*Bs[l*64 + lane];
    }
    #pragma unroll
    for (int l = 0; l < 32; ++l){
      h = fmaf(ev[l], h, gv[l]);
      pbw[l*65 + lane] = h*Cs[l*64 + lane];
    }
    __syncthreads();
    {
      const float* rp = &pbw[jl*65 + (lo ? 0 : 32)];
      float s0=0.f, s1=0.f, s2=0.f, s3=0.f;
      #pragma unroll
      for (int n = 0; n < 32; n += 4){
        s0 += rp[n]; s1 += rp[n+1]; s2 += rp[n+2]; s3 += rp[n+3];
      }
      float p = (s0+s1)+(s2+s3);
      p += __shfl_xor(p, 32);
      if (lo) yT[bd + c0 + jl] = p;
    }
    __syncthreads();
  }
}

// ---------------- yT -> y + epilogue, split out ----------------
__global__ void k_ytrans(const float* __restrict__ yT, const float* __restrict__ xs,
                         const float* __restrict__ xz, const float* __restrict__ D_p,
                         us* __restrict__ h, us* __restrict__ l){
  __shared__ float t[32][33];
  int b = blockIdx.z, d0 = blockIdx.y*32, l0 = blockIdx.x*32;
  int tx = threadIdx.x, ty = threadIdx.y;
  for (int i = ty; i < 32; i += 8)
    t[i][tx] = yT[((size_t)(b*512 + d0 + i))*Ll + l0 + tx];
  __syncthreads();
  for (int i = ty; i < 32; i += 8){
    int d = d0 + tx;
    size_t bl = (size_t)b*Ll + l0 + i;
    float p  = t[tx][i];
    float u  = xs[bl*512 + d];
    float zv = xz[bl*1024 + 512 + d];
    float v = (p + D_p[d]*u) * (zv * sigf(zv));
    wsplit(v, h, l, bl*512 + d);
  }
}

// ---------------- pack attention A/B operands from fused qkv ----------------
__global__ void k_pack_ab(const float* __restrict__ qkv,
                          const float* __restrict__ rhm, const float* __restrict__ rwm,
                          us* __restrict__ Ahp, us* __restrict__ Alp,
                          us* __restrict__ Bhp, us* __restrict__ Blp){
  int idx = blockIdx.x*256 + threadIdx.x;          // B*H*L*128
  int dd = idx & 127;
  int i  = (idx >> 7) & 1023;
  int h  = (idx >> 17) & 3;
  int b  = idx >> 19;
  float av, bv;
  if (dd < 64){
    size_t q = (size_t)(b*Ll + i)*768 + h*64 + dd;
    av = qkv[q]; bv = qkv[q + 256];
  } else {
    int d = dd - 64;
    av = rhm[(h*64+d)*32 + (i & 31)] + rwm[(h*64+d)*32 + (i >> 5)];
    bv = qkv[(size_t)(b*Ll + i)*768 + h*64 + d];
  }
  wsplit(av, Ahp, Alp, idx);
  wsplit(bv, Bhp, Blp, idx);
}

// ---------------- V transpose from qkv (split out): -> vT (B,256,L) -------------
__global__ void k_vtrans(const float* __restrict__ qkv, us* __restrict__ h,
                         us* __restrict__ l){
  __shared__ float t[32][33];
  int b = blockIdx.z, c0 = blockIdx.y*32, j0 = blockIdx.x*32;
  for (int i = threadIdx.y; i < 32; i += 8)
    t[i][threadIdx.x] = qkv[(size_t)(b*Ll + j0 + i)*768 + 512 + c0 + threadIdx.x];
  __syncthreads();
  for (int i = threadIdx.y; i < 32; i += 8){
    size_t o = ((size_t)(b*C2 + c0 + i))*Ll + j0 + threadIdx.x;
    wsplit(t[threadIdx.x][i], h, l, o);
  }
}

// ---------------- row softmax, IN-PLACE split output ----------------------------
__global__ void __launch_bounds__(256) k_softmax(float* __restrict__ e){
  __shared__ float red[4];
  __shared__ float red2[4];
  size_t row = blockIdx.x;
  float* p = e + row*1024;
  int t = threadIdx.x;
  float v0 = p[t], v1 = p[t+256], v2 = p[t+512], v3 = p[t+768];
  float mx = fmaxf(fmaxf(v0,v1), fmaxf(v2,v3));
  #pragma unroll
  for (int off=32; off; off>>=1) mx = fmaxf(mx, __shfl_xor(mx, off));
  if ((t&63)==0) red[t>>6] = mx;
  __syncthreads();
  mx = fmaxf(fmaxf(red[0],red[1]), fmaxf(red[2],red[3]));
  v0 = __expf(v0-mx); v1 = __expf(v1-mx); v2 = __expf(v2-mx); v3 = __expf(v3-mx);
  float s = v0+v1+v2+v3;
  #pragma unroll
  for (int off=32; off; off>>=1) s += __shfl_xor(s, off);
  if ((t&63)==0) red2[t>>6] = s;
  __syncthreads();
  s = red2[0]+red2[1]+red2[2]+red2[3];
  float inv = 1.0f/s;
  us* ph = (us*)p;   // hi at [j], lo at [1024+j]
  float r0 = v0*inv, r1 = v1*inv, r2 = v2*inv, r3 = v3*inv;
  us h0 = bfh(r0), h1 = bfh(r1), h2 = bfh(r2), h3 = bfh(r3);
  ph[t]      = h0; ph[1024+t]      = bfh(r0 - bff(h0));
  ph[t+256]  = h1; ph[1024+t+256]  = bfh(r1 - bff(h1));
  ph[t+512]  = h2; ph[1024+t+512]  = bfh(r2 - bff(h2));
  ph[t+768]  = h3; ph[1024+t+768]  = bfh(r3 - bff(h3));
}

// ---------------- fused ym*ctx + reshape-reinterpret (split out) ----------------
__global__ void k_mulshuf(const float* __restrict__ ym, const float* __restrict__ ctx,
                          us* __restrict__ h, us* __restrict__ l){
  __shared__ float t[32][33];
  int b = blockIdx.z >> 2, s1 = blockIdx.z & 3;
  int c0 = blockIdx.y*32, s00 = blockIdx.x*32;
  for (int i = threadIdx.y; i < 32; i += 8){
    int c = c0 + i;
    int ll = c*4 + s1;
    size_t off = ((size_t)(b*Ll + ll))*C2 + s00 + threadIdx.x;
    t[i][threadIdx.x] = ym[off] * ctx[off];
  }
  __syncthreads();
  for (int i = threadIdx.y; i < 32; i += 8){
    int s0 = s00 + i, c = c0 + threadIdx.x;
    int s = s1*256 + s0;
    wsplit(t[threadIdx.x][i], h, l, ((size_t)(b*Ll + s))*C2 + c);
  }
}

// ---------------- scalar gates ga/gb ----------------
__global__ void __launch_bounds__(256) k_gates(
    const float* __restrict__ ap, const float* __restrict__ bp,
    const float* __restrict__ Wg, const float* __restrict__ bg, float* __restrict__ g){
  __shared__ float ra[4], rb[4];
  int bl = blockIdx.x; int t = threadIdx.x;
  float sa = 0.f, sb = 0.f;
  const float* a = ap + (size_t)bl*512;
  const float* bq = bp + (size_t)bl*512;
  for (int pp = t; pp < 512; pp += 256){ float w = Wg[pp]; sa = fmaf(w, a[pp], sa); sb = fmaf(w, bq[pp], sb); }
  #pragma unroll
  for (int off=32; off; off>>=1){ sa += __shfl_xor(sa,off); sb += __shfl_xor(sb,off); }
  if ((t&63)==0){ ra[t>>6]=sa; rb[t>>6]=sb; }
  __syncthreads();
  if (t==0){
    float b0 = bg[0];
    g[bl]        = sigf(ra[0]+ra[1]+ra[2]+ra[3] + b0);
    g[4096 + bl] = sigf(rb[0]+rb[1]+rb[2]+rb[3] + b0);
  }
}

// ---------------- final gated combine, transposed write ----------------
__global__ void k_final(const float* __restrict__ ap, const float* __restrict__ bp,
                        const float* __restrict__ g, float* __restrict__ out){
  int bpid = blockIdx.x; int b = bpid >> 9, p = bpid & 511;
  for (int l = threadIdx.x; l < Ll; l += 256){
    int bl = b*Ll + l;
    float ga = g[bl], gb = g[4096 + bl];
    out[((size_t)(b*Pp + p) << 10) + l] =
        ga*ap[(size_t)bl*512 + p] + gb*bp[(size_t)bl*512 + p];
  }
}

// ---------------- host helper ----------------
static inline void hgemm(hipStream_t s, const us* Ah, const us* Al, const us* Bh, const us* Bl,
                         float* C, const float* bias, int M, int N, int K,
                         int lda, int ldb, int ldc, int act){
  dim3 g(N/64, M/64, 1), blk(256);
  k_hgemm<<<g, blk, 0, s>>>(Ah,Al,Bh,Bl,C,bias,M,N,K,lda,ldb,ldc, 0,0,0,0,0,0, act,
                            nullptr, nullptr);
}

extern "C" void kernel_launch(void* const* d_in, const int* in_sizes, int n_in,
                              void* d_out, int out_size, void* d_ws, size_t ws_size,
                              hipStream_t stream) {
  const float* x      = (const float*)d_in[0];
  const float* rh_c   = (const float*)d_in[1];
  const float* rw_c   = (const float*)d_in[2];
  const float* gate_w = (const float*)d_in[3];
  const float* gate_b = (const float*)d_in[4];
  const float* W_in   = (const float*)d_in[5];
  const float* conv_w = (const float*)d_in[6];
  const float* conv_b = (const float*)d_in[7];
  const float* W_x    = (const float*)d_in[8];
  const float* W_dt   = (const float*)d_in[9];
  const float* b_dt   = (const float*)d_in[10];
  const float* A_log  = (const float*)d_in[11];
  const float* D_p    = (const float*)d_in[12];
  const float* W_out  = (const float*)d_in[13];
  const float* Wq     = (const float*)d_in[14];
  const float* bq     = (const float*)d_in[15];
  const float* Wk     = (const float*)d_in[16];
  const float* bk     = (const float*)d_in[17];
  const float* Wv     = (const float*)d_in[18];
  const float* bv     = (const float*)d_in[19];
  const float* rhm    = (const float*)d_in[20];
  const float* rwm    = (const float*)d_in[21];
  // d_in[22] reg_qk, d_in[23] reg_v: provably dead
  const float* Wa     = (const float*)d_in[24];
  const float* ba     = (const float*)d_in[25];
  const float* Wb     = (const float*)d_in[26];
  const float* bb     = (const float*)d_in[27];
  const float* Wg     = (const float*)d_in[28];
  const float* bg     = (const float*)d_in[29];
  float* out = (float*)d_out;
  float* ws  = (float*)d_ws;

  // fp32 slot layout (floats), ~131 MB total
  float* seq    = ws;                       // 1,048,576
  float* x2seq  = ws +  1048576;            // 1,048,576 (x2 split)
  float* qkv    = ws +  2097152;            // 3,145,728 (qt|kt|vt fused; then mamba splits)
  float* Abuf   = ws +  5242880;            // 2,097,152 (energy A split / dtT)
  float* Bbuf   = ws +  7340032;            // 2,097,152 (energy B split / dtuT)
  float* arena  = ws +  9437184;            // 16,777,216
  float* out2s  = ws + 26214400;            // 1,048,576 (PV split output lives here)
  float* out1   = ws + 27262976;            // 1,048,576 (seq split, then out1 split)
  float* aproj  = ws + 28311552;            // 2,097,152 (vT split parks here)
  float* bproj  = ws + 30408704;            // 2,097,152
  float* gates  = ws + 32505856;            // 8,192
  float* W2     = ws + 32514048;            // 196,608 (W2 split)
  // arena sub-layout (mamba phase):
  float* A2   = arena;                      // 3,145,728 (A2 split)
  float* ctx  = arena +  3145728;           // 1,048,576
  float* xz   = arena +  4194304;           // 4,194,304
  float* xs   = arena +  8388608;           // 2,097,152
  float* xdbl = arena + 10485760;           // 786,432 (stride 192)
  float* yT   = arena + 11272192;           // 2,097,152
  float* yb   = arena + 13369344;           // 2,097,152 (yb split)
  float* ym   = arena + 15466496;           // 1,048,576
  float* energy = arena;                    // attention phase

  // ushort split views
  us* seqh = (us*)out1;      us* seql = seqh + 1048576;
  us* x2h  = (us*)x2seq;     us* x2l  = x2h + 1048576;
  us* eAh  = (us*)Abuf;      us* eAl  = eAh + 2097152;
  us* eBh  = (us*)Bbuf;      us* eBl  = eBh + 2097152;
  us* vTh  = (us*)aproj;     us* vTl  = vTh + 1048576;
  us* wqkvh = (us*)arena;    us* wqkvl = wqkvh + 196608;   // dead before energy
  float* bqkv = arena + 196608;                            // 768 floats
  us* Ph   = (us*)energy;    us* Pl   = Ph + 1024;         // per-row interleave, lda=2048
  us* A2h  = (us*)A2;        us* A2l  = A2h + 3145728;
  us* W2h  = (us*)W2;        us* W2l  = W2h + 196608;
  us* Wm   = (us*)(qkv + 1048576);   // mamba weight splits (middle of dead qkv)
  us* Winh = Wm;             us* Winl = Wm + 262144;
  us* Woh  = Wm + 524288;    us* Wol  = Wm + 655360;
  us* Wah  = Wm + 786432;    us* Wal  = Wm + 917504;
  us* Wbh  = Wm + 1048576;   us* Wbl  = Wm + 1179648;
  us* Wxh  = Wm + 1310720;   us* Wxl  = Wm + 1409024;
  us* xsh  = (us*)qkv;       us* xsl  = (us*)(qkv + 2097152);  // qt / vt thirds
  us* ybh  = (us*)yb;        us* ybl  = ybh + 2097152;
  us* o1h  = (us*)out1;      us* o1l  = o1h + 1048576;
  us* o2h  = (us*)out2s;     us* o2l  = o2h + 1048576;     // PV split output
  float* dtT  = Abuf;        float* dtuT = Bbuf;

  // 1. transpose: seq fp32 + seq split + x2 split
  k_transpose<<<dim3(32,16,4), dim3(32,8), 0, stream>>>(x, rh_c, rw_c, seq,
                                                        seqh, seql, x2h, x2l);

  // ---- attention ----
  k_wprep_a<<<772, 256, 0, stream>>>(Wq, Wk, Wv, bq, bk, bv, wqkvh, wqkvl, bqkv);
  // qkv = x2 @ [Wq;Wk;Wv]^T + bias, one N=768 GEMM
  hgemm(stream, x2h, x2l, wqkvh, wqkvl, qkv, bqkv, 4096,768,256, 256,256,768, 0);
  k_pack_ab<<<8192, 256, 0, stream>>>(qkv, rhm, rwm, eAh, eAl, eBh, eBl);
  k_vtrans<<<dim3(32,8,4), dim3(32,8), 0, stream>>>(qkv, vTh, vTl);
  // energy[z] (M=N=1024,K=128), z=b*4+h, 128² tile
  {
    dim3 g(8, 8, 16), blk(256);
    k_h128<<<g, blk, 0, stream>>>(eAh, eAl, eBh, eBl, energy, nullptr,
        1024,1024,128, 128,128,1024,
        4L*131072, 131072, 4L*131072, 131072, 4L*1048576, 1048576, 0);
  }
  k_softmax<<<16384, 256, 0, stream>>>(energy);   // in-place split
  // PV: split output written directly to out2 slot
  {
    dim3 g(1, 16, 16), blk(256);
    k_hgemm<<<g, blk, 0, stream>>>(Ph, Pl, vTh, vTl, nullptr, nullptr,
        1024,64,1024, 2048,1024,256,
        8388608, 2097152, 262144, 65536, 262144, 64, 0, o2h, o2l);
  }

  // ---- mamba (arena reused; qkv dead after vtrans) ----
  k_wprep_m<<<3713, 256, 0, stream>>>(W_in, W_out, Wa, Wb, gate_w, W_x,
      Winh, Winl, Woh, Wol, Wah, Wal, Wbh, Wbl, W2h, W2l, Wxh, Wxl);
  k_im2col<<<12288, 256, 0, stream>>>(seq, A2h, A2l);
  hgemm(stream, A2h, A2l, W2h, W2l, ctx, gate_b, 4096,256,768, 768,768,256, 1);
  // xz = seq @ W_in^T, 128² tile
  {
    dim3 g(8, 32, 1), blk(256);
    k_h128<<<g, blk, 0, stream>>>(seqh, seql, Winh, Winl, xz, nullptr,
        4096,1024,256, 256,256,1024, 0,0,0,0,0,0, 0);
  }
  k_dwconv<<<8192, 256, 0, stream>>>(xz, conv_w, conv_b, xs, xsh, xsl);
  hgemm(stream, xsh, xsl, Wxh, Wxl, xdbl, nullptr, 4096,192,512, 512,512,XDW, 0);
  k_pret<<<dim3(32,16,4), dim3(32,8), 0, stream>>>(xdbl, xs, W_dt, b_dt, dtT, dtuT);
  k_scan7<<<512, 256, 0, stream>>>(dtT, dtuT, xdbl, A_log, yT);
  k_ytrans<<<dim3(32,16,4), dim3(32,8), 0, stream>>>(yT, xs, xz, D_p, ybh, ybl);
  hgemm(stream, ybh, ybl, Woh, Wol, ym, nullptr, 4096,256,512, 512,512,256, 0);
  k_mulshuf<<<dim3(8,8,16), dim3(32,8), 0, stream>>>(ym, ctx, o1h, o1l);

  // ---- fusion head ----
  hgemm(stream, o1h, o1l, Wah, Wal, aproj, ba, 4096,512,256, 256,256,512, 0);
  hgemm(stream, o2h, o2l, Wbh, Wbl, bproj, bb, 4096,512,256, 256,256,512, 0);
  k_gates<<<4096, 256, 0, stream>>>(aproj, bproj, Wg, bg, gates);
  k_final<<<2048, 256, 0, stream>>>(aproj, bproj, gates, out);
}